// Round 1
// 432.650 us; speedup vs baseline: 1.1508x; 1.1508x over previous
//
#include <hip/hip_runtime.h>

// TemporalKplanesEncoding: out[p, :] = sum_{k=0..2} bilinear(plane_k, inp[p,k], inp[p,3])
// planes: [F=32, H=128, W=256] f32.  N = 2097152 points.
//
// R3 strategy: R2 binned points by t-row so gathers hit a 192 KB working set,
// but the 256 MB out-write stream thrashes the 4 MB/XCD L2, pushing gathers to
// L3 (~7 TB/s effective -> ~440 us in the sample kernel). R3 stages the bin's
// row pair into LDS (96 KB = 3 planes x 2 rows x 256 texels x 16 feats) and
// gathers at LDS bandwidth. Features split into two 16-wide halves to fit LDS;
// g_tr re-laid-out as [k][half][y][x][16f] so staging is contiguous.

#define NPTS 2097152
#define FEAT 32
#define PW 256
#define PH 128
#define SFEAT 16                       // features per pass (half)
#define PLANE_ELEMS (FEAT * PH * PW)   // 4 MB per plane (elems = 2^20)
#define NBINS 128
#define BIN_CAP 24576                  // mean 16384/bin, ~64 sigma headroom
#define NCHUNKS 4                      // sample blocks per (bin, half)

// transposed planes, layout [k][h][y][x][16f]:
// float offset = ((k*2 + h)*PH + y)*PW*SFEAT + x*SFEAT + f
__device__ float g_tr[3 * PLANE_ELEMS];

__global__ __launch_bounds__(256) void transpose_kernel(
    const float* __restrict__ p0,
    const float* __restrict__ p1,
    const float* __restrict__ p2) {
    int idx = blockIdx.x * 256 + threadIdx.x; // output-linear over [k][h][y][x][f]
    int f = idx & 15;
    int x = (idx >> 4) & 255;
    int y = (idx >> 12) & 127;
    int h = (idx >> 19) & 1;
    int k = idx >> 20;
    const float* src = (k == 0) ? p0 : (k == 1) ? p1 : p2;
    g_tr[idx] = src[(h * SFEAT + f) * (PH * PW) + y * PW + x];
}

__global__ __launch_bounds__(128) void zero_counts_kernel(int* counts) {
    counts[threadIdx.x] = 0;
}

// 256 blocks x 1024 threads x 8 points: LDS-aggregated counting scatter by t-row.
__global__ __launch_bounds__(1024) void scatter_kernel(
    const float* __restrict__ inp,
    float4* __restrict__ s_coords,
    int* __restrict__ s_ids,
    int* __restrict__ counts) {
    __shared__ int hist[NBINS];
    __shared__ int base[NBINS];
    int tid = threadIdx.x;
    if (tid < NBINS) hist[tid] = 0;
    __syncthreads();

    float4 c[8];
    int tag[8];
    int p0 = blockIdx.x * 8192 + tid;
#pragma unroll
    for (int i = 0; i < 8; ++i) {
        c[i] = reinterpret_cast<const float4*>(inp)[p0 + i * 1024];
        float y = fminf(fmaxf((c[i].w + 1.0f) * 63.5f, 0.0f), 127.0f);
        int bin = (int)floorf(y); // 0..127
        int lpos = atomicAdd(&hist[bin], 1); // block-local, <= 8192
        tag[i] = (bin << 16) | lpos;
    }
    __syncthreads();
    if (tid < NBINS) base[tid] = atomicAdd(&counts[tid], hist[tid]);
    __syncthreads();
#pragma unroll
    for (int i = 0; i < 8; ++i) {
        int bin = tag[i] >> 16;
        int pos = base[bin] + (tag[i] & 0xffff);
        int idx = bin * BIN_CAP + pos;
        s_coords[idx] = c[i];
        s_ids[idx] = p0 + i * 1024;
    }
}

// grid (2 halves, NCHUNKS, NBINS); 1024 threads = 256 points x 4 feature-lanes.
// Stage bin's 2 rows x 3 planes x 16 feats (96 KB) into LDS, then all gathers
// are ds_read_b128 from LDS. Out-writes are 64 B contiguous per point-half;
// halves of the same bin are adjacent in dispatch so lines combine in L2.
__global__ __launch_bounds__(1024) void sample_lds_kernel(
    const float4* __restrict__ s_coords,
    const int* __restrict__ s_ids,
    const int* __restrict__ counts,
    float* __restrict__ out) {
    __shared__ __align__(16) float lds[6 * PW * SFEAT]; // 96 KB: [k*2+dy][x][16f]

    const int h = blockIdx.x;      // feature half
    const int chunk = blockIdx.y;  // 0..NCHUNKS-1
    const int bin = blockIdx.z;
    const int tid = threadIdx.x;

    // --- stage: 6 regions x 16 KB, fully coalesced (contiguous in g_tr) ---
    const int row0 = bin;
    const int row1 = min(bin + 1, PH - 1);
#pragma unroll
    for (int i = 0; i < 6; ++i) {         // region i = k*2 + dy (tid < 1024)
        int k = i >> 1;
        int r = (i & 1) ? row1 : row0;
        const float4* src = reinterpret_cast<const float4*>(
            g_tr + ((size_t)((k * 2 + h) * PH + r)) * (PW * SFEAT));
        reinterpret_cast<float4*>(lds)[(i << 10) + tid] = src[tid];
    }
    __syncthreads();

    const int cnt = counts[bin];
    const int f4 = tid & 3;
    const int fo = f4 << 2;               // float offset within 16-feat half
    const int pid = tid >> 2;             // 0..255

    for (int s0 = chunk * 256; s0 < cnt; s0 += NCHUNKS * 256) {
        int slot = s0 + pid;
        if (slot < cnt) {
            int idx = bin * BIN_CAP + slot;
            float4 c = s_coords[idx];     // 4 lanes broadcast-load same 16 B
            int id = s_ids[idx];

            float y = fminf(fmaxf((c.w + 1.0f) * 63.5f, 0.0f), 127.0f);
            float wy = y - (float)bin;    // y0 == bin by scatter construction
            float omy = 1.0f - wy;

            float4 acc = make_float4(0.0f, 0.0f, 0.0f, 0.0f);
            const float cxs[3] = {c.x, c.y, c.z};
#pragma unroll
            for (int k = 0; k < 3; ++k) { // k compile-time (unrolled) -> no scratch
                float x = fminf(fmaxf((cxs[k] + 1.0f) * 127.5f, 0.0f), 255.0f);
                float x0f = floorf(x);
                float wx = x - x0f;
                float omx = 1.0f - wx;
                int x0 = (int)x0f;
                int x1 = min(x0 + 1, PW - 1);

                const float* L0 = lds + (k * 2) * (PW * SFEAT);
                const float* L1 = L0 + (PW * SFEAT);
                float4 v00 = *reinterpret_cast<const float4*>(L0 + (x0 << 4) + fo);
                float4 v01 = *reinterpret_cast<const float4*>(L0 + (x1 << 4) + fo);
                float4 v10 = *reinterpret_cast<const float4*>(L1 + (x0 << 4) + fo);
                float4 v11 = *reinterpret_cast<const float4*>(L1 + (x1 << 4) + fo);

                float w00 = omx * omy;
                float w01 = wx * omy;
                float w10 = omx * wy;
                float w11 = wx * wy;

                acc.x += v00.x * w00 + v01.x * w01 + v10.x * w10 + v11.x * w11;
                acc.y += v00.y * w00 + v01.y * w01 + v10.y * w10 + v11.y * w11;
                acc.z += v00.z * w00 + v01.z * w01 + v10.z * w10 + v11.z * w11;
                acc.w += v00.w * w00 + v01.w * w01 + v10.w * w10 + v11.w * w11;
            }
            // 64 B contiguous per point-half
            *reinterpret_cast<float4*>(out + ((size_t)id << 5) + (h << 4) + fo) = acc;
        }
    }
}

// Fallback path (unsorted, global gathers), used when ws is too small.
__device__ __forceinline__ float4 bilinear_sum_full(float4 c, int f4) {
    int h = f4 >> 2;
    int fo = (f4 & 3) << 2;
    float y = fminf(fmaxf((c.w + 1.0f) * 63.5f, 0.0f), 127.0f);
    float y0f = floorf(y);
    float wy = y - y0f;
    int y0 = (int)y0f;
    int y1 = min(y0 + 1, PH - 1);
    float omy = 1.0f - wy;

    float4 acc = make_float4(0.0f, 0.0f, 0.0f, 0.0f);
    const float cxs[3] = {c.x, c.y, c.z};
#pragma unroll
    for (int k = 0; k < 3; ++k) {
        float x = fminf(fmaxf((cxs[k] + 1.0f) * 127.5f, 0.0f), 255.0f);
        float x0f = floorf(x);
        float wx = x - x0f;
        int x0 = (int)x0f;
        int x1 = min(x0 + 1, PW - 1);
        float omx = 1.0f - wx;

        float w00 = omx * omy;
        float w01 = wx * omy;
        float w10 = omx * wy;
        float w11 = wx * wy;

        const float* b0 = g_tr + ((size_t)((k * 2 + h) * PH + y0)) * (PW * SFEAT);
        const float* b1 = g_tr + ((size_t)((k * 2 + h) * PH + y1)) * (PW * SFEAT);
        float4 v00 = *reinterpret_cast<const float4*>(b0 + (x0 << 4) + fo);
        float4 v01 = *reinterpret_cast<const float4*>(b0 + (x1 << 4) + fo);
        float4 v10 = *reinterpret_cast<const float4*>(b1 + (x0 << 4) + fo);
        float4 v11 = *reinterpret_cast<const float4*>(b1 + (x1 << 4) + fo);

        acc.x += v00.x * w00 + v01.x * w01 + v10.x * w10 + v11.x * w11;
        acc.y += v00.y * w00 + v01.y * w01 + v10.y * w10 + v11.y * w11;
        acc.z += v00.z * w00 + v01.z * w01 + v10.z * w10 + v11.z * w11;
        acc.w += v00.w * w00 + v01.w * w01 + v10.w * w10 + v11.w * w11;
    }
    return acc;
}

__global__ __launch_bounds__(256) void sample_kernel(
    const float* __restrict__ inp,
    float* __restrict__ out) {
    int tid = blockIdx.x * 256 + threadIdx.x;
    int p  = tid >> 3;
    int f4 = tid & 7;
    float4 c = reinterpret_cast<const float4*>(inp)[p];
    float4 acc = bilinear_sum_full(c, f4);
    reinterpret_cast<float4*>(out)[tid] = acc;
}

extern "C" void kernel_launch(void* const* d_in, const int* in_sizes, int n_in,
                              void* d_out, int out_size, void* d_ws, size_t ws_size,
                              hipStream_t stream) {
    const float* inp = (const float*)d_in[0];
    const float* p0 = (const float*)d_in[1];
    const float* p1 = (const float*)d_in[2];
    const float* p2 = (const float*)d_in[3];
    float* out = (float*)d_out;

    transpose_kernel<<<(3 * PLANE_ELEMS) / 256, 256, 0, stream>>>(p0, p1, p2);

    const size_t coords_bytes = (size_t)NBINS * BIN_CAP * sizeof(float4); // 50 MB
    const size_t ids_bytes    = (size_t)NBINS * BIN_CAP * sizeof(int);    // 12.6 MB
    const size_t need = coords_bytes + ids_bytes + NBINS * sizeof(int);

    if (ws_size >= need) {
        float4* s_coords = (float4*)d_ws;
        int* s_ids = (int*)((char*)d_ws + coords_bytes);
        int* counts = (int*)((char*)d_ws + coords_bytes + ids_bytes);

        zero_counts_kernel<<<1, NBINS, 0, stream>>>(counts);
        scatter_kernel<<<NPTS / 8192, 1024, 0, stream>>>(inp, s_coords, s_ids, counts);
        dim3 grid(2, NCHUNKS, NBINS); // h fastest: both halves of a bin co-resident
        sample_lds_kernel<<<grid, 1024, 0, stream>>>(s_coords, s_ids, counts, out);
    } else {
        sample_kernel<<<(NPTS * 8) / 256, 256, 0, stream>>>(inp, out);
    }
}

// Round 2
// 386.037 us; speedup vs baseline: 1.2898x; 1.1207x over previous
//
#include <hip/hip_runtime.h>
#include <hip/hip_fp16.h>

// TemporalKplanesEncoding: out[p, :] = sum_{k=0..2} bilinear(plane_k, inp[p,k], inp[p,3])
// planes: [F=32, H=128, W=256] f32.  N = 2097152 points.
//
// R4 strategy: R3's remaining cost was (a) 64 B scattered half-line out-writes
// (each out line written by two different blocks), (b) a separate transpose
// kernel with stride-128KB scalar reads, (c) scatter writing 20 B across two
// scattered stores per point. R4 stores LDS texels as fp16 so ALL 32 features
// of the bin's working set fit in 96 KB -> one block writes full 128 B lines.
// The transpose kernel is gone: sample stages directly from the original
// planes via a 32 KB LDS bounce (coalesced reads, swizzled conflict-free
// transposed writes). Scatter packs (id,wy) into 16 B/point.

#define NPTS 2097152
#define FEAT 32
#define PW 256
#define PH 128
#define NBINS 128
#define BIN_CAP 24576                  // mean 16384/bin, ~64 sigma headroom
#define NCHUNKS 4                      // sample blocks per bin

__global__ __launch_bounds__(128) void zero_counts_kernel(int* counts) {
    counts[threadIdx.x] = 0;
}

// 256 blocks x 1024 threads x 8 points: LDS-aggregated counting scatter by
// t-row. Payload = {cx0, cx1, cx2, (id<<11 | wy_q11)} -> one 16 B store/point.
__global__ __launch_bounds__(1024) void scatter_kernel(
    const float* __restrict__ inp,
    float4* __restrict__ s_pts,
    int* __restrict__ counts) {
    __shared__ int hist[NBINS];
    __shared__ int base[NBINS];
    int tid = threadIdx.x;
    if (tid < NBINS) hist[tid] = 0;
    __syncthreads();

    float4 c[8];
    int tag[8];
    unsigned int pw[8];
    int p0 = blockIdx.x * 8192 + tid;
#pragma unroll
    for (int i = 0; i < 8; ++i) {
        c[i] = reinterpret_cast<const float4*>(inp)[p0 + i * 1024];
        float y = fminf(fmaxf((c[i].w + 1.0f) * 63.5f, 0.0f), 127.0f);
        float bf = floorf(y);
        int bin = (int)bf;                       // 0..127
        int wyq = (int)((y - bf) * 2048.0f);     // 11-bit wy, trunc <= 2047
        pw[i] = ((unsigned int)(p0 + i * 1024) << 11) | (unsigned int)wyq;
        int lpos = atomicAdd(&hist[bin], 1);     // block-local, <= 8192
        tag[i] = (bin << 16) | lpos;
    }
    __syncthreads();
    if (tid < NBINS) base[tid] = atomicAdd(&counts[tid], hist[tid]);
    __syncthreads();
#pragma unroll
    for (int i = 0; i < 8; ++i) {
        int bin = tag[i] >> 16;
        int pos = base[bin] + (tag[i] & 0xffff);
        s_pts[bin * BIN_CAP + pos] =
            make_float4(c[i].x, c[i].y, c[i].z, __uint_as_float(pw[i]));
    }
}

__device__ __forceinline__ unsigned int pk16(float a, float b) {
    __half2 h = __floats2half2_rn(a, b);
    return *reinterpret_cast<unsigned int*>(&h);
}
__device__ __forceinline__ float2 up16(unsigned int u) {
    __half2 h = *reinterpret_cast<__half2*>(&u);
    return __half22float2(h);
}

// grid (NCHUNKS, NBINS); 1024 threads = 256 points x 4 feature-lanes.
// LDS: tex = 6 rows x 256 x x 4 slots x 16 B fp16 (96 KB, slot-swizzled by
// (slot + (x>>1))&3 so both staging b128 writes and 4-lane gathers spread
// across all 32 banks) + 32 KB f32 bounce for the in-kernel transpose.
__global__ __launch_bounds__(1024) void sample_lds_kernel(
    const float* __restrict__ pl0,
    const float* __restrict__ pl1,
    const float* __restrict__ pl2,
    const float4* __restrict__ s_pts,
    const int* __restrict__ counts,
    float* __restrict__ out) {
    __shared__ uint4 tex[6 * PW * 4];    // 96 KB: [row i=k*2+dy][x][swz slot]
    __shared__ float bounce[FEAT * PW];  // 32 KB: [f][x] for one row

    const int chunk = blockIdx.x;
    const int bin = blockIdx.y;
    const int tid = threadIdx.x;
    const int r1 = min(bin + 1, PH - 1);
    const float* planes[3] = {pl0, pl1, pl2};

    // --- stage 6 rows: global(coalesced) -> bounce -> fp16 swizzled tex ---
    for (int i = 0; i < 6; ++i) {
        const float* src = planes[i >> 1] + ((i & 1) ? r1 : bin) * PW;
        {   // phase A: 32 f-slices x 256 x, 1 KB contiguous per wave
            int f = tid >> 6;              // 0..15 (covers f and f+16)
            int x4 = (tid & 63) << 2;
            float4 a = *reinterpret_cast<const float4*>(src + f * (PH * PW) + x4);
            float4 b = *reinterpret_cast<const float4*>(src + (f + 16) * (PH * PW) + x4);
            *reinterpret_cast<float4*>(bounce + f * PW + x4) = a;
            *reinterpret_cast<float4*>(bounce + (f + 16) * PW + x4) = b;
        }
        __syncthreads();
        {   // phase B: transpose-read (conflict-free), pack fp16, swizzled b128 write
            int slot = tid >> 8;           // 0..3 (8 feats per slot)
            int x = tid & 255;
            const float* bp = bounce + (slot << 3) * PW + x;
            uint4 v;
            v.x = pk16(bp[0],      bp[PW]);
            v.y = pk16(bp[2 * PW], bp[3 * PW]);
            v.z = pk16(bp[4 * PW], bp[5 * PW]);
            v.w = pk16(bp[6 * PW], bp[7 * PW]);
            int swz = (slot + ((x >> 1) & 3)) & 3;
            tex[(i << 10) | (x << 2) | swz] = v;
        }
        __syncthreads();
    }

    const int cnt = min(counts[bin], BIN_CAP);
    const int pid = tid >> 2;              // 0..255
    const int f4 = tid & 3;                // feature slot: feats f4*8..f4*8+7

    for (int s0 = chunk * 256; s0 < cnt; s0 += NCHUNKS * 256) {
        int slot = s0 + pid;
        if (slot < cnt) {
            float4 c = s_pts[bin * BIN_CAP + slot]; // 4 lanes broadcast 16 B
            unsigned int pw = __float_as_uint(c.w);
            int id = pw >> 11;
            float wy = (float)(pw & 2047u) * (1.0f / 2048.0f);
            float omy = 1.0f - wy;

            float a0 = 0, a1 = 0, a2 = 0, a3 = 0, a4 = 0, a5 = 0, a6 = 0, a7 = 0;
            const float cx[3] = {c.x, c.y, c.z};
#pragma unroll
            for (int k = 0; k < 3; ++k) {
                float x = fminf(fmaxf((cx[k] + 1.0f) * 127.5f, 0.0f), 255.0f);
                float x0f = floorf(x);
                float wx = x - x0f;
                float omx = 1.0f - wx;
                int x0 = (int)x0f;
                int x1 = min(x0 + 1, PW - 1);
                float w00 = omx * omy, w01 = wx * omy;
                float w10 = omx * wy, w11 = wx * wy;

                int b0 = (k * 2) << 10;
                int b1 = b0 + 1024;
                int i0 = (x0 << 2) | ((f4 + ((x0 >> 1) & 3)) & 3);
                int i1 = (x1 << 2) | ((f4 + ((x1 >> 1) & 3)) & 3);
                uint4 t00 = tex[b0 | i0];
                uint4 t01 = tex[b0 | i1];
                uint4 t10 = tex[b1 | i0];
                uint4 t11 = tex[b1 | i1];
#define ACC(T, W) { float2 u0 = up16(T.x), u1 = up16(T.y), u2 = up16(T.z), u3 = up16(T.w); \
                a0 += u0.x * W; a1 += u0.y * W; a2 += u1.x * W; a3 += u1.y * W; \
                a4 += u2.x * W; a5 += u2.y * W; a6 += u3.x * W; a7 += u3.y * W; }
                ACC(t00, w00) ACC(t01, w01) ACC(t10, w10) ACC(t11, w11)
#undef ACC
            }
            // full 128 B line: 4 lanes x 2 float4
            float* op = out + ((size_t)id << 5) + (f4 << 3);
            *reinterpret_cast<float4*>(op) = make_float4(a0, a1, a2, a3);
            *reinterpret_cast<float4*>(op + 4) = make_float4(a4, a5, a6, a7);
        }
    }
}

// Fallback path (unsorted, scalar gathers from original planes) — only used
// if the workspace is too small; correctness-first, never expected to run.
__global__ __launch_bounds__(256) void sample_fallback_kernel(
    const float* __restrict__ inp,
    const float* __restrict__ pl0,
    const float* __restrict__ pl1,
    const float* __restrict__ pl2,
    float* __restrict__ out) {
    int t = blockIdx.x * 256 + threadIdx.x; // over NPTS*8
    int p = t >> 3;
    int f4 = t & 7;                          // 4 feats per lane
    float4 c = reinterpret_cast<const float4*>(inp)[p];
    float y = fminf(fmaxf((c.w + 1.0f) * 63.5f, 0.0f), 127.0f);
    float y0f = floorf(y);
    float wy = y - y0f;
    int y0 = (int)y0f;
    int y1 = min(y0 + 1, PH - 1);
    float omy = 1.0f - wy;
    const float* planes[3] = {pl0, pl1, pl2};
    const float cx[3] = {c.x, c.y, c.z};
    float acc[4] = {0.f, 0.f, 0.f, 0.f};
#pragma unroll
    for (int k = 0; k < 3; ++k) {
        float x = fminf(fmaxf((cx[k] + 1.0f) * 127.5f, 0.0f), 255.0f);
        float x0f = floorf(x);
        float wx = x - x0f;
        int x0 = (int)x0f;
        int x1 = min(x0 + 1, PW - 1);
        float omx = 1.0f - wx;
        float w00 = omx * omy, w01 = wx * omy, w10 = omx * wy, w11 = wx * wy;
#pragma unroll
        for (int j = 0; j < 4; ++j) {
            const float* pf = planes[k] + (size_t)(f4 * 4 + j) * (PH * PW);
            acc[j] += pf[y0 * PW + x0] * w00 + pf[y0 * PW + x1] * w01
                    + pf[y1 * PW + x0] * w10 + pf[y1 * PW + x1] * w11;
        }
    }
    *reinterpret_cast<float4*>(out + ((size_t)p << 5) + (f4 << 2)) =
        make_float4(acc[0], acc[1], acc[2], acc[3]);
}

extern "C" void kernel_launch(void* const* d_in, const int* in_sizes, int n_in,
                              void* d_out, int out_size, void* d_ws, size_t ws_size,
                              hipStream_t stream) {
    const float* inp = (const float*)d_in[0];
    const float* pl0 = (const float*)d_in[1];
    const float* pl1 = (const float*)d_in[2];
    const float* pl2 = (const float*)d_in[3];
    float* out = (float*)d_out;

    const size_t pts_bytes = (size_t)NBINS * BIN_CAP * sizeof(float4); // 50.3 MB
    const size_t need = pts_bytes + NBINS * sizeof(int);

    if (ws_size >= need) {
        float4* s_pts = (float4*)d_ws;
        int* counts = (int*)((char*)d_ws + pts_bytes);

        zero_counts_kernel<<<1, NBINS, 0, stream>>>(counts);
        scatter_kernel<<<NPTS / 8192, 1024, 0, stream>>>(inp, s_pts, counts);
        dim3 grid(NCHUNKS, NBINS);
        sample_lds_kernel<<<grid, 1024, 0, stream>>>(pl0, pl1, pl2, s_pts, counts, out);
    } else {
        sample_fallback_kernel<<<(NPTS * 8) / 256, 256, 0, stream>>>(inp, pl0, pl1, pl2, out);
    }
}